// Round 2
// baseline (361.915 us; speedup 1.0000x reference)
//
#include <hip/hip_runtime.h>

#define HIMG 192
#define HWSZ (192*192)
#define NWX  24

typedef __bf16 bf16;
typedef __bf16 bf16x4 __attribute__((ext_vector_type(4)));
typedef __bf16 bf16x8 __attribute__((ext_vector_type(8)));
typedef float  f32x4  __attribute__((ext_vector_type(4)));

#define MFMA(a,b,c) __builtin_amdgcn_mfma_f32_16x16x32_bf16((a),(b),(c),0,0,0)
// bank swizzle: spreads both {16 consecutive rows} and {8q+t permuted rows} over 8 slots
#define SW(r) ((((((r)&7) ^ (((r)>>3)<<1))) & 7) << 4)

static __device__ __forceinline__ bf16x8 ldg8(const float* p) {
    const float4 u = ((const float4*)p)[0];
    const float4 v = ((const float4*)p)[1];
    bf16x8 r;
    r[0]=(bf16)u.x; r[1]=(bf16)u.y; r[2]=(bf16)u.z; r[3]=(bf16)u.w;
    r[4]=(bf16)v.x; r[5]=(bf16)v.y; r[6]=(bf16)v.z; r[7]=(bf16)v.w;
    return r;
}
static __device__ __forceinline__ bf16x4 pk4b(f32x4 v, float4 b) {
    bf16x4 r; r[0]=(bf16)(v[0]+b.x); r[1]=(bf16)(v[1]+b.y);
    r[2]=(bf16)(v[2]+b.z); r[3]=(bf16)(v[3]+b.w); return r;
}
static __device__ __forceinline__ bf16x4 pk4bs(f32x4 v, float4 b, float s) {
    bf16x4 r; r[0]=(bf16)((v[0]+b.x)*s); r[1]=(bf16)((v[1]+b.y)*s);
    r[2]=(bf16)((v[2]+b.z)*s); r[3]=(bf16)((v[3]+b.w)*s); return r;
}
static __device__ __forceinline__ bf16x4 pk4c(f32x4 v, float b) {
    bf16x4 r; r[0]=(bf16)(v[0]+b); r[1]=(bf16)(v[1]+b);
    r[2]=(bf16)(v[2]+b); r[3]=(bf16)(v[3]+b); return r;
}
static __device__ __forceinline__ bf16x4 pk4s(f32x4 v, float s) {
    bf16x4 r; r[0]=(bf16)(v[0]*s); r[1]=(bf16)(v[1]*s);
    r[2]=(bf16)(v[2]*s); r[3]=(bf16)(v[3]*s); return r;
}
static __device__ __forceinline__ bf16x4 pk4(f32x4 v) {
    bf16x4 r; r[0]=(bf16)v[0]; r[1]=(bf16)v[1]; r[2]=(bf16)v[2]; r[3]=(bf16)v[3]; return r;
}
static __device__ __forceinline__ bf16x8 cat8(bf16x4 a, bf16x4 b) {
    bf16x8 r; r[0]=a[0]; r[1]=a[1]; r[2]=a[2]; r[3]=a[3];
    r[4]=b[0]; r[5]=b[1]; r[6]=b[2]; r[7]=b[3]; return r;
}

// Precompute relative-position bias table: wb[h][i][j], 4*64*64 f32 = 64KB
__global__ __launch_bounds__(256) void bias_setup(const float* __restrict__ rpb,
                                                  float* __restrict__ wb) {
    const int e = blockIdx.x * 256 + threadIdx.x;   // 0..16383
    const int h = e >> 12, i = (e >> 6) & 63, j = e & 63;
    const int dy = (i >> 3) - (j >> 3) + 7;
    const int dx = (i & 7)  - (j & 7)  + 7;
    wb[e] = rpb[(dy * 15 + dx) * 4 + h];
}

template<int WSB>
__global__ __launch_bounds__(256, 4)
void swin_fused(const float* __restrict__ x, const float* __restrict__ qkv_w,
                const float* __restrict__ qkv_b, const float* __restrict__ proj_w,
                const float* __restrict__ proj_b, const float* __restrict__ rpb,
                const float* __restrict__ wb, float* __restrict__ out)
{
    __shared__ char sX[16384];   // [64 tokens] x 256B bf16 (X window; later attn-out)

    const int tid  = threadIdx.x;
    const int lane = tid & 63;
    const int wvid = tid >> 6;       // wave id == head id
    const int lo   = lane & 15;
    const int hi   = lane >> 4;

    // XCD-chunked swizzle: 4608 blocks = 8 XCDs x 576 windows (one batch per XCD)
    const int bid   = blockIdx.x;
    const int batch = bid & 7;
    const int wrem  = bid >> 3;      // 0..575
    const int wy    = wrem / NWX;
    const int wx    = wrem - wy * NWX;

    const f32x4 FZ = {0.f, 0.f, 0.f, 0.f};

    // ---------------- Phase 1: gather+roll X window -> LDS bf16 (swizzled) ----
    {
        const int t  = lane;
        int hh = wy*8 + (t >> 3) + 4; if (hh >= HIMG) hh -= HIMG;
        int ww = wx*8 + (t & 7)  + 4; if (ww >= HIMG) ww -= HIMG;
        const float* xp = x + (long)batch * 128 * HWSZ + hh * HIMG + ww;
        char* const wp = sX + t * 256;
        const int swz = SW(t);
        #pragma unroll
        for (int g = 0; g < 4; ++g) {
            const int c0 = wvid*32 + g*8;
            bf16x8 v;
            #pragma unroll
            for (int e = 0; e < 8; ++e) v[e] = (bf16)xp[(c0 + e) * HWSZ];
            *(bf16x8*)(wp + ((2*c0) ^ swz)) = v;
        }
    }
    __syncthreads();   // B0

    const float SCALE = 0.17677669529663687f;   // 32^-0.5
    const int prow = ((lo >> 2) << 3) + (lo & 3);   // permuted-row base (d/token perm)

    bf16x8 qf[4], kf[4];

    // ---------------- Phase 2a: Q^T = Wq @ X^T (head wvid), B-frag ready ------
    {
        f32x4 acc[2][4];
        #pragma unroll
        for (int a = 0; a < 2; ++a)
            #pragma unroll
            for (int n = 0; n < 4; ++n) acc[a][n] = FZ;
        #pragma unroll
        for (int kb = 0; kb < 4; ++kb) {
            bf16x8 xf[4];
            #pragma unroll
            for (int n = 0; n < 4; ++n) {
                const int row = n*16 + lo;
                xf[n] = *(const bf16x8*)(sX + row*256 + ((kb*64 + hi*16) ^ SW(row)));
            }
            const int coff = kb*32 + hi*8;
            const bf16x8 w0 = ldg8(qkv_w + (wvid*32 + prow    ) * 128 + coff);
            const bf16x8 w1 = ldg8(qkv_w + (wvid*32 + prow + 4) * 128 + coff);
            #pragma unroll
            for (int n = 0; n < 4; ++n) {
                acc[0][n] = MFMA(w0, xf[n], acc[0][n]);
                acc[1][n] = MFMA(w1, xf[n], acc[1][n]);
            }
        }
        const float4 b0 = *(const float4*)(qkv_b + wvid*32 + hi*8);
        const float4 b1 = *(const float4*)(qkv_b + wvid*32 + hi*8 + 4);
        #pragma unroll
        for (int n = 0; n < 4; ++n)
            qf[n] = cat8(pk4bs(acc[0][n], b0, SCALE), pk4bs(acc[1][n], b1, SCALE));
    }

    // ---------------- Phase 2b: K^T = Wk @ X^T, A-frag ready (tokens permuted) -
    {
        f32x4 acc[2][4];
        #pragma unroll
        for (int a = 0; a < 2; ++a)
            #pragma unroll
            for (int m = 0; m < 4; ++m) acc[a][m] = FZ;
        #pragma unroll
        for (int kb = 0; kb < 4; ++kb) {
            bf16x8 xf[4];
            #pragma unroll
            for (int m = 0; m < 4; ++m) {
                const int row = (m >> 1)*32 + (m & 1)*4 + prow;   // T'(m, lo)
                xf[m] = *(const bf16x8*)(sX + row*256 + ((kb*64 + hi*16) ^ SW(row)));
            }
            const int coff = kb*32 + hi*8;
            const bf16x8 w0 = ldg8(qkv_w + (128 + wvid*32 + prow    ) * 128 + coff);
            const bf16x8 w1 = ldg8(qkv_w + (128 + wvid*32 + prow + 4) * 128 + coff);
            #pragma unroll
            for (int m = 0; m < 4; ++m) {
                acc[0][m] = MFMA(w0, xf[m], acc[0][m]);
                acc[1][m] = MFMA(w1, xf[m], acc[1][m]);
            }
        }
        const float4 b0 = *(const float4*)(qkv_b + 128 + wvid*32 + hi*8);
        const float4 b1 = *(const float4*)(qkv_b + 128 + wvid*32 + hi*8 + 4);
        #pragma unroll
        for (int m = 0; m < 4; ++m)
            kf[m] = cat8(pk4b(acc[0][m], b0), pk4b(acc[1][m], b1));
    }

    // ---------------- Phase 3: S^T = K @ Q^T, bias+mask, softmax, pack P ------
    f32x4 s[4][4];
    #pragma unroll
    for (int m = 0; m < 4; ++m)
        #pragma unroll
        for (int n = 0; n < 4; ++n)
            s[m][n] = MFMA(kf[m], qf[n], FZ);

    const bool ey = (wy == 23), ex = (wx == 23);
    const float* wbh = wb + wvid * 4096;
    #pragma unroll
    for (int n = 0; n < 4; ++n) {
        const int i_ = n*16 + lo;
        const int yi = i_ >> 3, xi = i_ & 7;
        const int ri = (ey ? (yi < 4 ? 1 : 2) : 0) * 3 + (ex ? (xi < 4 ? 1 : 2) : 0);
        #pragma unroll
        for (int m = 0; m < 4; ++m) {
            const int j0 = (m >> 1)*32 + hi*8 + (m & 1)*4;   // permuted j base
            f32x4 bb = FZ;
            if (WSB) bb = *(const f32x4*)(wbh + i_*64 + j0);
            #pragma unroll
            for (int r = 0; r < 4; ++r) {
                const int j_ = j0 + r;
                const int yj = j_ >> 3, xj = j_ & 7;
                float bias;
                if (WSB) bias = bb[r];
                else     bias = rpb[((yi - yj + 7) * 15 + (xi - xj + 7)) * 4 + wvid];
                const int rj = (ey ? (yj < 4 ? 1 : 2) : 0) * 3 + (ex ? (xj < 4 ? 1 : 2) : 0);
                s[m][n][r] += bias + ((ri != rj) ? -100.0f : 0.0f);
            }
        }
    }
    float rinv[4];
    #pragma unroll
    for (int n = 0; n < 4; ++n) {
        float mx = -1e30f;
        #pragma unroll
        for (int m = 0; m < 4; ++m)
            #pragma unroll
            for (int r = 0; r < 4; ++r) mx = fmaxf(mx, s[m][n][r]);
        mx = fmaxf(mx, __shfl_xor(mx, 16));
        mx = fmaxf(mx, __shfl_xor(mx, 32));
        float sum = 0.f;
        #pragma unroll
        for (int m = 0; m < 4; ++m)
            #pragma unroll
            for (int r = 0; r < 4; ++r) {
                const float p = __expf(s[m][n][r] - mx);
                s[m][n][r] = p; sum += p;
            }
        sum += __shfl_xor(sum, 16);
        sum += __shfl_xor(sum, 32);
        rinv[n] = 1.0f / sum;
    }
    bf16x8 pf[2][4];   // P^T B-frags: pf[kb][n]
    #pragma unroll
    for (int kb = 0; kb < 2; ++kb)
        #pragma unroll
        for (int n = 0; n < 4; ++n)
            pf[kb][n] = cat8(pk4(s[kb*2][n]), pk4(s[kb*2 + 1][n]));

    // ---------------- Phase 2c: V = X @ Wv^T, A-frag ready (tokens permuted) --
    bf16x8 vf[2][2];   // vf[o][kb]
    {
        f32x4 av[4][2];
        #pragma unroll
        for (int m = 0; m < 4; ++m)
            #pragma unroll
            for (int o = 0; o < 2; ++o) av[m][o] = FZ;
        #pragma unroll
        for (int kb = 0; kb < 4; ++kb) {
            bf16x8 xv[4];
            #pragma unroll
            for (int m = 0; m < 4; ++m) {
                const int row = (m >> 1)*32 + (m & 1)*4 + prow;   // T'(m, lo)
                xv[m] = *(const bf16x8*)(sX + row*256 + ((kb*64 + hi*16) ^ SW(row)));
            }
            const int coff = kb*32 + hi*8;
            const bf16x8 w0 = ldg8(qkv_w + (256 + wvid*32 + lo)      * 128 + coff);
            const bf16x8 w1 = ldg8(qkv_w + (256 + wvid*32 + 16 + lo) * 128 + coff);
            #pragma unroll
            for (int m = 0; m < 4; ++m) {
                av[m][0] = MFMA(xv[m], w0, av[m][0]);
                av[m][1] = MFMA(xv[m], w1, av[m][1]);
            }
        }
        const float bv0 = qkv_b[256 + wvid*32 + lo];
        const float bv1 = qkv_b[256 + wvid*32 + 16 + lo];
        #pragma unroll
        for (int kb = 0; kb < 2; ++kb) {
            vf[0][kb] = cat8(pk4c(av[kb*2][0], bv0), pk4c(av[kb*2 + 1][0], bv0));
            vf[1][kb] = cat8(pk4c(av[kb*2][1], bv1), pk4c(av[kb*2 + 1][1], bv1));
        }
    }
    __syncthreads();   // B1: all sX reads done; attn-out may overwrite

    // ---------------- Phase 4: O^T = V^T @ P^T (all registers) ----------------
    {
        f32x4 o0[2][4];
        #pragma unroll
        for (int o = 0; o < 2; ++o)
            #pragma unroll
            for (int n = 0; n < 4; ++n) o0[o][n] = FZ;
        #pragma unroll
        for (int kb = 0; kb < 2; ++kb)
            #pragma unroll
            for (int o = 0; o < 2; ++o)
                #pragma unroll
                for (int n = 0; n < 4; ++n)
                    o0[o][n] = MFMA(vf[o][kb], pf[kb][n], o0[o][n]);
        // attn-out (bf16, [t][c]) into sX; apply softmax normalization here
        #pragma unroll
        for (int o = 0; o < 2; ++o) {
            const int cb = wvid*64 + o*32 + hi*8;    // byte col of 4 channels
            #pragma unroll
            for (int n = 0; n < 4; ++n) {
                const int t = n*16 + lo;
                *(bf16x4*)(sX + t*256 + (cb ^ SW(t))) = pk4s(o0[o][n], rinv[n]);
            }
        }
    }
    __syncthreads();   // B2

    // ---------------- Phase 5: out^T = Wproj @ AO^T, scatter ------------------
    {
        f32x4 pr[2][4];
        #pragma unroll
        for (int a = 0; a < 2; ++a)
            #pragma unroll
            for (int n = 0; n < 4; ++n) pr[a][n] = FZ;
        #pragma unroll
        for (int kb = 0; kb < 4; ++kb) {
            bf16x8 af[4];
            #pragma unroll
            for (int n = 0; n < 4; ++n) {
                const int row = n*16 + lo;
                af[n] = *(const bf16x8*)(sX + row*256 + ((kb*64 + hi*16) ^ SW(row)));
            }
            const int coff = kb*32 + hi*8;
            const bf16x8 w0 = ldg8(proj_w + (wvid*32 + lo)      * 128 + coff);
            const bf16x8 w1 = ldg8(proj_w + (wvid*32 + 16 + lo) * 128 + coff);
            #pragma unroll
            for (int n = 0; n < 4; ++n) {
                pr[0][n] = MFMA(w0, af[n], pr[0][n]);
                pr[1][n] = MFMA(w1, af[n], pr[1][n]);
            }
        }
        #pragma unroll
        for (int a = 0; a < 2; ++a) {
            const int ocb = wvid*32 + a*16 + hi*4;
            const float4 pb = *(const float4*)(proj_b + ocb);
            #pragma unroll
            for (int n = 0; n < 4; ++n) {
                const int t = n*16 + lo;
                int hh = wy*8 + (t >> 3) + 4; if (hh >= HIMG) hh -= HIMG;
                int ww = wx*8 + (t & 7)  + 4; if (ww >= HIMG) ww -= HIMG;
                float* op = out + (long)(batch*128 + ocb) * HWSZ + hh*HIMG + ww;
                op[0]      = pr[a][n][0] + pb.x;
                op[HWSZ]   = pr[a][n][1] + pb.y;
                op[2*HWSZ] = pr[a][n][2] + pb.z;
                op[3*HWSZ] = pr[a][n][3] + pb.w;
            }
        }
    }
}

extern "C" void kernel_launch(void* const* d_in, const int* in_sizes, int n_in,
                              void* d_out, int out_size, void* d_ws, size_t ws_size,
                              hipStream_t stream) {
    const float* x      = (const float*)d_in[0];
    const float* qkv_w  = (const float*)d_in[1];
    const float* qkv_b  = (const float*)d_in[2];
    const float* proj_w = (const float*)d_in[3];
    const float* proj_b = (const float*)d_in[4];
    const float* rpb    = (const float*)d_in[5];
    float* out = (float*)d_out;

    if (ws_size >= 16384 * sizeof(float)) {
        float* wbias = (float*)d_ws;
        bias_setup<<<64, 256, 0, stream>>>(rpb, wbias);
        swin_fused<1><<<4608, 256, 0, stream>>>(x, qkv_w, qkv_b, proj_w, proj_b, rpb, wbias, out);
    } else {
        swin_fused<0><<<4608, 256, 0, stream>>>(x, qkv_w, qkv_b, proj_w, proj_b, rpb, nullptr, out);
    }
}

// Round 3
// 243.469 us; speedup vs baseline: 1.4865x; 1.4865x over previous
//
#include <hip/hip_runtime.h>

#define HIMG 192
#define HWSZ (192*192)
#define NWX  24

typedef __bf16 bf16;
typedef __bf16 bf16x4 __attribute__((ext_vector_type(4)));
typedef __bf16 bf16x8 __attribute__((ext_vector_type(8)));
typedef float  f32x4  __attribute__((ext_vector_type(4)));

#define MFMA(a,b,c) __builtin_amdgcn_mfma_f32_16x16x32_bf16((a),(b),(c),0,0,0)
// bank swizzle: spreads both {16 consecutive rows} and {8q+t permuted rows} over 8 slots
#define SW(r) ((((((r)&7) ^ (((r)>>3)<<1))) & 7) << 4)

static __device__ __forceinline__ bf16x8 ldg8(const float* p) {
    const float4 u = ((const float4*)p)[0];
    const float4 v = ((const float4*)p)[1];
    bf16x8 r;
    r[0]=(bf16)u.x; r[1]=(bf16)u.y; r[2]=(bf16)u.z; r[3]=(bf16)u.w;
    r[4]=(bf16)v.x; r[5]=(bf16)v.y; r[6]=(bf16)v.z; r[7]=(bf16)v.w;
    return r;
}
template<int WSB>
static __device__ __forceinline__ bf16x8 ldw(const float* wf, const bf16* wh, int off) {
    if (WSB) return *(const bf16x8*)(wh + off);
    return ldg8(wf + off);
}
static __device__ __forceinline__ bf16x4 pk4b(f32x4 v, float4 b) {
    bf16x4 r; r[0]=(bf16)(v[0]+b.x); r[1]=(bf16)(v[1]+b.y);
    r[2]=(bf16)(v[2]+b.z); r[3]=(bf16)(v[3]+b.w); return r;
}
static __device__ __forceinline__ bf16x4 pk4bs(f32x4 v, float4 b, float s) {
    bf16x4 r; r[0]=(bf16)((v[0]+b.x)*s); r[1]=(bf16)((v[1]+b.y)*s);
    r[2]=(bf16)((v[2]+b.z)*s); r[3]=(bf16)((v[3]+b.w)*s); return r;
}
static __device__ __forceinline__ bf16x4 pk4c(f32x4 v, float b) {
    bf16x4 r; r[0]=(bf16)(v[0]+b); r[1]=(bf16)(v[1]+b);
    r[2]=(bf16)(v[2]+b); r[3]=(bf16)(v[3]+b); return r;
}
static __device__ __forceinline__ bf16x4 pk4s(f32x4 v, float s) {
    bf16x4 r; r[0]=(bf16)(v[0]*s); r[1]=(bf16)(v[1]*s);
    r[2]=(bf16)(v[2]*s); r[3]=(bf16)(v[3]*s); return r;
}
static __device__ __forceinline__ bf16x4 pk4(f32x4 v) {
    bf16x4 r; r[0]=(bf16)v[0]; r[1]=(bf16)v[1]; r[2]=(bf16)v[2]; r[3]=(bf16)v[3]; return r;
}
static __device__ __forceinline__ bf16x8 cat8(bf16x4 a, bf16x4 b) {
    bf16x8 r; r[0]=a[0]; r[1]=a[1]; r[2]=a[2]; r[3]=a[3];
    r[4]=b[0]; r[5]=b[1]; r[6]=b[2]; r[7]=b[3]; return r;
}

// Setup: bias table wb[h][i][j] (4*64*64 f32) + bf16 copies of qkv_w (384x128)
// and proj_w (128x128) into workspace.
__global__ __launch_bounds__(256) void setup_ws(const float* __restrict__ rpb,
                                                const float* __restrict__ qkv_w,
                                                const float* __restrict__ proj_w,
                                                float* __restrict__ wb,
                                                bf16* __restrict__ hqkv,
                                                bf16* __restrict__ hproj) {
    const int e = blockIdx.x * 256 + threadIdx.x;   // 0..81919
    if (e < 16384) {
        const int h = e >> 12, i = (e >> 6) & 63, j = e & 63;
        const int dy = (i >> 3) - (j >> 3) + 7;
        const int dx = (i & 7)  - (j & 7)  + 7;
        wb[e] = rpb[(dy * 15 + dx) * 4 + h];
    } else if (e < 16384 + 49152) {
        const int i = e - 16384;
        hqkv[i] = (bf16)qkv_w[i];
    } else {
        const int i = e - 16384 - 49152;
        hproj[i] = (bf16)proj_w[i];
    }
}

template<int WSB>
__global__ __launch_bounds__(256, 3)
void swin_fused(const float* __restrict__ x, const float* __restrict__ qkv_w,
                const float* __restrict__ qkv_b, const float* __restrict__ proj_w,
                const float* __restrict__ proj_b, const float* __restrict__ rpb,
                const float* __restrict__ wb, const bf16* __restrict__ hqkv,
                const bf16* __restrict__ hproj, float* __restrict__ out)
{
    __shared__ char sX[16384];   // [64 tokens] x 256B bf16 (X window; later attn-out)

    const int tid  = threadIdx.x;
    const int lane = tid & 63;
    const int wvid = tid >> 6;       // wave id == head id
    const int lo   = lane & 15;
    const int hi   = lane >> 4;

    // XCD-chunked swizzle: 4608 blocks = 8 XCDs x 576 windows (one batch per XCD)
    const int bid   = blockIdx.x;
    const int batch = bid & 7;
    const int wrem  = bid >> 3;      // 0..575
    const int wy    = wrem / NWX;
    const int wx    = wrem - wy * NWX;

    const f32x4 FZ = {0.f, 0.f, 0.f, 0.f};

    // ---------------- Phase 1: gather+roll X window -> LDS bf16 (swizzled) ----
    {
        const int t  = lane;
        int hh = wy*8 + (t >> 3) + 4; if (hh >= HIMG) hh -= HIMG;
        int ww = wx*8 + (t & 7)  + 4; if (ww >= HIMG) ww -= HIMG;
        const float* xp = x + (long)batch * 128 * HWSZ + hh * HIMG + ww;
        char* const wp = sX + t * 256;
        const int swz = SW(t);
        #pragma unroll
        for (int g = 0; g < 4; ++g) {
            const int c0 = wvid*32 + g*8;
            bf16x8 v;
            #pragma unroll
            for (int e = 0; e < 8; ++e) v[e] = (bf16)xp[(c0 + e) * HWSZ];
            *(bf16x8*)(wp + ((2*c0) ^ swz)) = v;
        }
    }
    __syncthreads();   // B0

    const float SCALE = 0.17677669529663687f;   // 32^-0.5
    const int prow = ((lo >> 2) << 3) + (lo & 3);   // permuted-row base (d/token perm)

    bf16x8 qf[4], kf[4];

    // ---------------- Phase 2a: Q^T = Wq @ X^T (head wvid), B-frag ready ------
    {
        f32x4 acc[2][4];
        #pragma unroll
        for (int a = 0; a < 2; ++a)
            #pragma unroll
            for (int n = 0; n < 4; ++n) acc[a][n] = FZ;
        #pragma unroll
        for (int kb = 0; kb < 4; ++kb) {
            bf16x8 xf[4];
            #pragma unroll
            for (int n = 0; n < 4; ++n) {
                const int row = n*16 + lo;
                xf[n] = *(const bf16x8*)(sX + row*256 + ((kb*64 + hi*16) ^ SW(row)));
            }
            const int coff = kb*32 + hi*8;
            const bf16x8 w0 = ldw<WSB>(qkv_w, hqkv, (wvid*32 + prow    ) * 128 + coff);
            const bf16x8 w1 = ldw<WSB>(qkv_w, hqkv, (wvid*32 + prow + 4) * 128 + coff);
            #pragma unroll
            for (int n = 0; n < 4; ++n) {
                acc[0][n] = MFMA(w0, xf[n], acc[0][n]);
                acc[1][n] = MFMA(w1, xf[n], acc[1][n]);
            }
        }
        const float4 b0 = *(const float4*)(qkv_b + wvid*32 + hi*8);
        const float4 b1 = *(const float4*)(qkv_b + wvid*32 + hi*8 + 4);
        #pragma unroll
        for (int n = 0; n < 4; ++n)
            qf[n] = cat8(pk4bs(acc[0][n], b0, SCALE), pk4bs(acc[1][n], b1, SCALE));
    }

    // ---------------- Phase 2b: K^T = Wk @ X^T, A-frag ready (tokens permuted) -
    {
        f32x4 acc[2][4];
        #pragma unroll
        for (int a = 0; a < 2; ++a)
            #pragma unroll
            for (int m = 0; m < 4; ++m) acc[a][m] = FZ;
        #pragma unroll
        for (int kb = 0; kb < 4; ++kb) {
            bf16x8 xf[4];
            #pragma unroll
            for (int m = 0; m < 4; ++m) {
                const int row = (m >> 1)*32 + (m & 1)*4 + prow;   // T'(m, lo)
                xf[m] = *(const bf16x8*)(sX + row*256 + ((kb*64 + hi*16) ^ SW(row)));
            }
            const int coff = kb*32 + hi*8;
            const bf16x8 w0 = ldw<WSB>(qkv_w, hqkv, (128 + wvid*32 + prow    ) * 128 + coff);
            const bf16x8 w1 = ldw<WSB>(qkv_w, hqkv, (128 + wvid*32 + prow + 4) * 128 + coff);
            #pragma unroll
            for (int m = 0; m < 4; ++m) {
                acc[0][m] = MFMA(w0, xf[m], acc[0][m]);
                acc[1][m] = MFMA(w1, xf[m], acc[1][m]);
            }
        }
        const float4 b0 = *(const float4*)(qkv_b + 128 + wvid*32 + hi*8);
        const float4 b1 = *(const float4*)(qkv_b + 128 + wvid*32 + hi*8 + 4);
        #pragma unroll
        for (int m = 0; m < 4; ++m)
            kf[m] = cat8(pk4b(acc[0][m], b0), pk4b(acc[1][m], b1));
    }

    // ---------------- Phase 3: S^T = K @ Q^T, bias+mask, softmax, pack P ------
    f32x4 s[4][4];
    #pragma unroll
    for (int m = 0; m < 4; ++m)
        #pragma unroll
        for (int n = 0; n < 4; ++n)
            s[m][n] = MFMA(kf[m], qf[n], FZ);

    const bool ey = (wy == 23), ex = (wx == 23);
    const float* wbh = wb + wvid * 4096;
    #pragma unroll
    for (int n = 0; n < 4; ++n) {
        const int i_ = n*16 + lo;
        const int yi = i_ >> 3, xi = i_ & 7;
        const int ri = (ey ? (yi < 4 ? 1 : 2) : 0) * 3 + (ex ? (xi < 4 ? 1 : 2) : 0);
        #pragma unroll
        for (int m = 0; m < 4; ++m) {
            const int j0 = (m >> 1)*32 + hi*8 + (m & 1)*4;   // permuted j base
            f32x4 bb = FZ;
            if (WSB) bb = *(const f32x4*)(wbh + i_*64 + j0);
            #pragma unroll
            for (int r = 0; r < 4; ++r) {
                const int j_ = j0 + r;
                const int yj = j_ >> 3, xj = j_ & 7;
                float bias;
                if (WSB) bias = bb[r];
                else     bias = rpb[((yi - yj + 7) * 15 + (xi - xj + 7)) * 4 + wvid];
                const int rj = (ey ? (yj < 4 ? 1 : 2) : 0) * 3 + (ex ? (xj < 4 ? 1 : 2) : 0);
                s[m][n][r] += bias + ((ri != rj) ? -100.0f : 0.0f);
            }
        }
    }
    float rinv[4];
    #pragma unroll
    for (int n = 0; n < 4; ++n) {
        float mx = -1e30f;
        #pragma unroll
        for (int m = 0; m < 4; ++m)
            #pragma unroll
            for (int r = 0; r < 4; ++r) mx = fmaxf(mx, s[m][n][r]);
        mx = fmaxf(mx, __shfl_xor(mx, 16));
        mx = fmaxf(mx, __shfl_xor(mx, 32));
        float sum = 0.f;
        #pragma unroll
        for (int m = 0; m < 4; ++m)
            #pragma unroll
            for (int r = 0; r < 4; ++r) {
                const float p = __expf(s[m][n][r] - mx);
                s[m][n][r] = p; sum += p;
            }
        sum += __shfl_xor(sum, 16);
        sum += __shfl_xor(sum, 32);
        rinv[n] = 1.0f / sum;
    }
    bf16x8 pf[2][4];   // P^T B-frags: pf[kb][n]
    #pragma unroll
    for (int kb = 0; kb < 2; ++kb)
        #pragma unroll
        for (int n = 0; n < 4; ++n)
            pf[kb][n] = cat8(pk4(s[kb*2][n]), pk4(s[kb*2 + 1][n]));

    // ---------------- Phase 2c: V = X @ Wv^T, A-frag ready (tokens permuted) --
    bf16x8 vf[2][2];   // vf[o][kb]
    {
        f32x4 av[4][2];
        #pragma unroll
        for (int m = 0; m < 4; ++m)
            #pragma unroll
            for (int o = 0; o < 2; ++o) av[m][o] = FZ;
        #pragma unroll
        for (int kb = 0; kb < 4; ++kb) {
            bf16x8 xv[4];
            #pragma unroll
            for (int m = 0; m < 4; ++m) {
                const int row = (m >> 1)*32 + (m & 1)*4 + prow;   // T'(m, lo)
                xv[m] = *(const bf16x8*)(sX + row*256 + ((kb*64 + hi*16) ^ SW(row)));
            }
            const int coff = kb*32 + hi*8;
            const bf16x8 w0 = ldw<WSB>(qkv_w, hqkv, (256 + wvid*32 + lo)      * 128 + coff);
            const bf16x8 w1 = ldw<WSB>(qkv_w, hqkv, (256 + wvid*32 + 16 + lo) * 128 + coff);
            #pragma unroll
            for (int m = 0; m < 4; ++m) {
                av[m][0] = MFMA(xv[m], w0, av[m][0]);
                av[m][1] = MFMA(xv[m], w1, av[m][1]);
            }
        }
        const float bv0 = qkv_b[256 + wvid*32 + lo];
        const float bv1 = qkv_b[256 + wvid*32 + 16 + lo];
        #pragma unroll
        for (int kb = 0; kb < 2; ++kb) {
            vf[0][kb] = cat8(pk4c(av[kb*2][0], bv0), pk4c(av[kb*2 + 1][0], bv0));
            vf[1][kb] = cat8(pk4c(av[kb*2][1], bv1), pk4c(av[kb*2 + 1][1], bv1));
        }
    }
    __syncthreads();   // B1: all sX reads done; attn-out may overwrite

    // ---------------- Phase 4: O^T = V^T @ P^T (all registers) ----------------
    {
        f32x4 o0[2][4];
        #pragma unroll
        for (int o = 0; o < 2; ++o)
            #pragma unroll
            for (int n = 0; n < 4; ++n) o0[o][n] = FZ;
        #pragma unroll
        for (int kb = 0; kb < 2; ++kb)
            #pragma unroll
            for (int o = 0; o < 2; ++o)
                #pragma unroll
                for (int n = 0; n < 4; ++n)
                    o0[o][n] = MFMA(vf[o][kb], pf[kb][n], o0[o][n]);
        // attn-out (bf16, [t][c]) into sX; apply softmax normalization here
        #pragma unroll
        for (int o = 0; o < 2; ++o) {
            const int cb = wvid*64 + o*32 + hi*8;    // byte col of 4 channels
            #pragma unroll
            for (int n = 0; n < 4; ++n) {
                const int t = n*16 + lo;
                *(bf16x4*)(sX + t*256 + (cb ^ SW(t))) = pk4s(o0[o][n], rinv[n]);
            }
        }
    }
    __syncthreads();   // B2

    // ---------------- Phase 5: out^T = Wproj @ AO^T, scatter ------------------
    {
        f32x4 pr[2][4];
        #pragma unroll
        for (int a = 0; a < 2; ++a)
            #pragma unroll
            for (int n = 0; n < 4; ++n) pr[a][n] = FZ;
        #pragma unroll
        for (int kb = 0; kb < 4; ++kb) {
            bf16x8 af[4];
            #pragma unroll
            for (int n = 0; n < 4; ++n) {
                const int row = n*16 + lo;
                af[n] = *(const bf16x8*)(sX + row*256 + ((kb*64 + hi*16) ^ SW(row)));
            }
            const int coff = kb*32 + hi*8;
            const bf16x8 w0 = ldw<WSB>(proj_w, hproj, (wvid*32 + lo)      * 128 + coff);
            const bf16x8 w1 = ldw<WSB>(proj_w, hproj, (wvid*32 + 16 + lo) * 128 + coff);
            #pragma unroll
            for (int n = 0; n < 4; ++n) {
                pr[0][n] = MFMA(w0, af[n], pr[0][n]);
                pr[1][n] = MFMA(w1, af[n], pr[1][n]);
            }
        }
        #pragma unroll
        for (int a = 0; a < 2; ++a) {
            const int ocb = wvid*32 + a*16 + hi*4;
            const float4 pb = *(const float4*)(proj_b + ocb);
            #pragma unroll
            for (int n = 0; n < 4; ++n) {
                const int t = n*16 + lo;
                int hh = wy*8 + (t >> 3) + 4; if (hh >= HIMG) hh -= HIMG;
                int ww = wx*8 + (t & 7)  + 4; if (ww >= HIMG) ww -= HIMG;
                float* op = out + (long)(batch*128 + ocb) * HWSZ + hh*HIMG + ww;
                op[0]      = pr[a][n][0] + pb.x;
                op[HWSZ]   = pr[a][n][1] + pb.y;
                op[2*HWSZ] = pr[a][n][2] + pb.z;
                op[3*HWSZ] = pr[a][n][3] + pb.w;
            }
        }
    }
}

extern "C" void kernel_launch(void* const* d_in, const int* in_sizes, int n_in,
                              void* d_out, int out_size, void* d_ws, size_t ws_size,
                              hipStream_t stream) {
    const float* x      = (const float*)d_in[0];
    const float* qkv_w  = (const float*)d_in[1];
    const float* qkv_b  = (const float*)d_in[2];
    const float* proj_w = (const float*)d_in[3];
    const float* proj_b = (const float*)d_in[4];
    const float* rpb    = (const float*)d_in[5];
    float* out = (float*)d_out;

    // ws layout: [0,64K) f32 bias table | [64K,160K) bf16 qkv_w | [160K,192K) bf16 proj_w
    if (ws_size >= 196608) {
        float* wbias = (float*)d_ws;
        bf16*  hqkv  = (bf16*)((char*)d_ws + 65536);
        bf16*  hproj = (bf16*)((char*)d_ws + 65536 + 98304);
        setup_ws<<<320, 256, 0, stream>>>(rpb, qkv_w, proj_w, wbias, hqkv, hproj);
        swin_fused<1><<<4608, 256, 0, stream>>>(x, qkv_w, qkv_b, proj_w, proj_b, rpb,
                                                wbias, hqkv, hproj, out);
    } else {
        swin_fused<0><<<4608, 256, 0, stream>>>(x, qkv_w, qkv_b, proj_w, proj_b, rpb,
                                                nullptr, nullptr, nullptr, out);
    }
}